// Round 6
// baseline (262.278 us; speedup 1.0000x reference)
//
#include <hip/hip_runtime.h>

// TreeSoftmax: x [B=4, C=144, H=256, W=256] f32 -> same shape.
// 4-ary tree, node i (1..144) <-> channel i-1. parent(i) = (i-1)/4.
// res[i] = softmax_within_sibling_group(x)[i] * res[parent(i)].
//
// R6: R2/R5 showed the kernel is LATENCY-bound (95us, 2.35TB/s, ~1
// outstanding load/wave; compiler sinks register loads no matter what).
// Fix: structural MLP via global_load_lds DMA — fire-and-forget, no dest
// VGPR, cannot be sunk. One wave per block stages its own 64 pixels x 144
// channels (36KB LDS, no barrier needed), then computes from LDS.
// 4 blocks/CU resident; staging waves keep up to 63 x 256B in flight each
// while sibling waves compute -> HBM pipe stays fed.

typedef const __attribute__((address_space(1))) float gfloat;
typedef __attribute__((address_space(3))) float lfloat;

__device__ __forceinline__ void grp4s(float a, float b, float c, float d,
                                      float pr, float out[4]) {
    float m = fmaxf(fmaxf(a, b), fmaxf(c, d));
    float e0 = __expf(a - m);
    float e1 = __expf(b - m);
    float e2 = __expf(c - m);
    float e3 = __expf(d - m);
    float f = pr / (e0 + e1 + e2 + e3);   // parent prob folded into normalization
    out[0] = e0 * f;
    out[1] = e1 * f;
    out[2] = e2 * f;
    out[3] = e3 * f;
}

__global__ __launch_bounds__(64) void tree_softmax_kernel(
        const float* __restrict__ x, float* __restrict__ y) {
    __shared__ float lds[144 * 64];
    const int HW = 65536;              // channel stride in floats
    const int C  = 144;

    const int t    = threadIdx.x;          // 0..63 (one wave)
    const int blk  = blockIdx.x;           // 0..4095
    const int b    = blk >> 10;            // 1024 blocks per batch image
    const int pix0 = (blk & 1023) << 6;    // first pixel of this wave's 64
    const size_t base = (size_t)b * C * HW + (size_t)pix0;

    const float* __restrict__ xg = x + base + t;   // per-lane global src
    float*       __restrict__ yg = y + base + t;   // per-lane global dst

    // ---- stage: 144 fire-and-forget 256B DMA loads, LDS[c][lane] <- x ----
#pragma unroll
    for (int c = 0; c < 144; ++c) {
        __builtin_amdgcn_global_load_lds(
            (gfloat*)(xg + (size_t)c * HW),   // per-lane global address
            (lfloat*)(&lds[c * 64]),          // wave-uniform LDS base (+lane*4 in HW)
            4, 0, 0);
    }
    asm volatile("s_waitcnt vmcnt(0)" ::: "memory");
    __builtin_amdgcn_sched_barrier(0);

    // ---- compute from LDS (bank-conflict-free: lane t -> bank t%32, 2-way) --
#define L(c) lds[(c) * 64 + t]
    float o[4];

    // level 1: channels 0..3, parent prob = 1
    float r1[4];
    grp4s(L(0), L(1), L(2), L(3), 1.0f, r1);
#pragma unroll
    for (int c = 0; c < 4; ++c) __builtin_nontemporal_store(r1[c], &yg[c * HW]);

    // level 2: parents nodes 1..4 (r1), channels 4..19
    float r2[16];
#pragma unroll
    for (int p = 0; p < 4; ++p) {
        int c0 = 4 + 4 * p;
        grp4s(L(c0), L(c0 + 1), L(c0 + 2), L(c0 + 3), r1[p], o);
#pragma unroll
        for (int c = 0; c < 4; ++c) {
            __builtin_nontemporal_store(o[c], &yg[(c0 + c) * HW]);
            r2[4 * p + c] = o[c];
        }
    }

    // level 3: parents nodes 5..20 (r2), channels 20..83
    // keep channels 20..34 (nodes 21..35) as level-4 parents
    float keep[15];
#pragma unroll
    for (int p = 0; p < 16; ++p) {
        int c0 = 20 + 4 * p;
        grp4s(L(c0), L(c0 + 1), L(c0 + 2), L(c0 + 3), r2[p], o);
#pragma unroll
        for (int c = 0; c < 4; ++c) {
            int idx = 4 * p + c;            // 0..63
            __builtin_nontemporal_store(o[c], &yg[(c0 + c) * HW]);
            if (idx < 15) keep[idx] = o[c]; // compile-time predicate after unroll
        }
    }

    // level 4: parents nodes 21..35 (keep), channels 84..143
#pragma unroll
    for (int p = 0; p < 15; ++p) {
        int c0 = 84 + 4 * p;
        grp4s(L(c0), L(c0 + 1), L(c0 + 2), L(c0 + 3), keep[p], o);
#pragma unroll
        for (int c = 0; c < 4; ++c)
            __builtin_nontemporal_store(o[c], &yg[(c0 + c) * HW]);
    }
#undef L
}

extern "C" void kernel_launch(void* const* d_in, const int* in_sizes, int n_in,
                              void* d_out, int out_size, void* d_ws, size_t ws_size,
                              hipStream_t stream) {
    const float* x = (const float*)d_in[0];
    float* y = (float*)d_out;
    const int threads = 64;                       // one wave per block
    const int blocks  = (4 * 256 * 256) / 64;     // 4096 blocks
    tree_softmax_kernel<<<blocks, threads, 0, stream>>>(x, y);
}

// Round 7
// 255.395 us; speedup vs baseline: 1.0270x; 1.0270x over previous
//
#include <hip/hip_runtime.h>

// TreeSoftmax: x [B=4, C=144, H=256, W=256] f32 -> same shape.
// 4-ary tree, node i (1..144) <-> channel i-1. parent(i) = (i-1)/4.
// res[i] = softmax_within_sibling_group(x)[i] * res[parent(i)].
//
// R7 = R2 (TLP) + R6 (structural MLP) with counted-vmcnt pipelining:
//  - 4 waves/block, each wave owns 64 pixels + a PRIVATE 8KB LDS slice
//    -> no __syncthreads, no vmcnt(0) drain, waves free-run.
//  - 144 channels in 9 chunks of 16, double-buffered global_load_lds DMA
//    (fire-and-forget, compiler can't sink it). Iter k: s_waitcnt vmcnt(32)
//    [chunk k guaranteed landed: >=32 newer vmem ops exist], compute 4
//    sibling groups, store 16 channels, stage chunk k+2.
//  - 32KB LDS/block -> 5 blocks/CU cap; grid = 16 waves/CU resident.
//    In-flight ~64-128KB/CU >> Little's-law need for 6TB/s.

typedef const __attribute__((address_space(1))) float gfloat;
typedef __attribute__((address_space(3))) float lfloat;

__global__ __launch_bounds__(256, 4) void tree_softmax_kernel(
        const float* __restrict__ x, float* __restrict__ y) {
    constexpr int HW  = 65536;   // channel stride (floats)
    constexpr int C   = 144;
    constexpr int CH  = 16;      // channels per chunk
    constexpr int NCH = 9;       // chunks

    __shared__ float lds[4][2][CH][64];    // [wave][buf][chan][pixel] = 32 KB

    const int t     = threadIdx.x & 63;
    const int w     = threadIdx.x >> 6;
    const int gwave = blockIdx.x * 4 + w;      // 0..4095, one per 64 pixels
    const int b     = gwave >> 10;
    const int pix0  = (gwave & 1023) << 6;
    const size_t base = (size_t)b * C * HW + (size_t)pix0;

    const float* __restrict__ xg = x + base + t;
    float*       __restrict__ yg = y + base + t;

    // ---- prologue: stage chunks 0 and 1 (32 DMA loads in flight) ----
#pragma unroll
    for (int c = 0; c < CH; ++c)
        __builtin_amdgcn_global_load_lds((gfloat*)(xg + (size_t)c * HW),
                                         (lfloat*)&lds[w][0][c][0], 4, 0, 0);
#pragma unroll
    for (int c = 0; c < CH; ++c)
        __builtin_amdgcn_global_load_lds((gfloat*)(xg + (size_t)(CH + c) * HW),
                                         (lfloat*)&lds[w][1][c][0], 4, 0, 0);

    float par[35];   // results of channels 0..34 = nodes 1..35 (parents)

#pragma unroll
    for (int k = 0; k < NCH; ++k) {
        // Counted wait: chunk k's 16 loads are the oldest outstanding group.
        // k=0: only L1 (16) newer. k=1..7: L(k+1)+S(k-1) >= 32 newer.
        // k=8: only S7 (16) newer.
        if (k == 0 || k == NCH - 1)
            asm volatile("s_waitcnt vmcnt(16)" ::: "memory");
        else
            asm volatile("s_waitcnt vmcnt(32)" ::: "memory");

        // ---- compute this chunk's 4 sibling groups ----
#pragma unroll
        for (int g = 0; g < 4; ++g) {
            const int n  = k * 4 + g;     // parent-node index 0..35
            const int c0 = 4 * n;         // first child channel of group
            float a0 = lds[w][k & 1][4 * g + 0][t];
            float a1 = lds[w][k & 1][4 * g + 1][t];
            float a2 = lds[w][k & 1][4 * g + 2][t];
            float a3 = lds[w][k & 1][4 * g + 3][t];
            float pr = (n == 0) ? 1.0f : par[n - 1];
            float m  = fmaxf(fmaxf(a0, a1), fmaxf(a2, a3));
            float e0 = __expf(a0 - m);
            float e1 = __expf(a1 - m);
            float e2 = __expf(a2 - m);
            float e3 = __expf(a3 - m);
            float f  = pr / (e0 + e1 + e2 + e3);
            float o0 = e0 * f, o1 = e1 * f, o2 = e2 * f, o3 = e3 * f;
            yg[(size_t)(c0 + 0) * HW] = o0;
            yg[(size_t)(c0 + 1) * HW] = o1;
            yg[(size_t)(c0 + 2) * HW] = o2;
            yg[(size_t)(c0 + 3) * HW] = o3;
            if (c0 + 0 < 35) par[c0 + 0] = o0;   // compile-time predicates
            if (c0 + 1 < 35) par[c0 + 1] = o1;
            if (c0 + 2 < 35) par[c0 + 2] = o2;
            if (c0 + 3 < 35) par[c0 + 3] = o3;
        }

        // ---- stage chunk k+2 into the buffer just consumed ----
        if (k + 2 < NCH) {
#pragma unroll
            for (int c = 0; c < CH; ++c)
                __builtin_amdgcn_global_load_lds(
                    (gfloat*)(xg + (size_t)((k + 2) * CH + c) * HW),
                    (lfloat*)&lds[w][k & 1][c][0], 4, 0, 0);
        }
    }
}

extern "C" void kernel_launch(void* const* d_in, const int* in_sizes, int n_in,
                              void* d_out, int out_size, void* d_ws, size_t ws_size,
                              hipStream_t stream) {
    const float* x = (const float*)d_in[0];
    float* y = (float*)d_out;
    const int threads = 256;                       // 4 waves/block
    const int blocks  = (4 * 256 * 256) / (64 * 4);  // 1024 blocks
    tree_softmax_kernel<<<blocks, threads, 0, stream>>>(x, y);
}